// Round 3
// baseline (10187.630 us; speedup 1.0000x reference)
//
#include <hip/hip_runtime.h>
#include <hip/hip_bf16.h>

#define Bsz 256
#define Tt  512
#define Hh  128

// ws layout (floats):
//   Wt_ih [3][4][128][128]  per-block panels: [layer][hcTile][k][colp] colp=gate*32+wc
//   Wt_hh [3][4][128][128]  same layout
//   bias  [3][4][128]       permuted bih+bhh
//   hbuf  [2][3][256][128]  double-buffered hidden states
//   cbuf  [3][256][128]     cell states (in-place)
#define OFF_WTHH 196608
#define OFF_BIAS 393216
#define OFF_HBUF 394752
#define OFF_CBUF 591360
// total 689664 floats = 2.76 MB

__global__ void prep_kernel(const float* Wih0, const float* Whh0, const float* bih0, const float* bhh0,
                            const float* Wih1, const float* Whh1, const float* bih1, const float* bhh1,
                            const float* Wih2, const float* Whh2, const float* bih2, const float* bhh2,
                            float* ws)
{
    int gid = blockIdx.x * blockDim.x + threadIdx.x;   // 0..1535
    if (gid >= 3 * 512) return;
    int l = gid >> 9, gc = gid & 511;
    const float* Wih = (l == 0) ? Wih0 : (l == 1) ? Wih1 : Wih2;
    const float* Whh = (l == 0) ? Whh0 : (l == 1) ? Whh1 : Whh2;
    const float* bih = (l == 0) ? bih0 : (l == 1) ? bih1 : bih2;
    const float* bhh = (l == 0) ? bhh0 : (l == 1) ? bhh1 : bhh2;
    int Kin = (l == 0) ? 8 : 128;
    int gate = gc >> 7, hcT = (gc >> 5) & 3, wc = gc & 31;
    int colp = gate * 32 + wc;                      // block-local permuted column
    float* Pih = ws + ((size_t)(l * 4 + hcT) * 128) * 128;
    float* Phh = ws + OFF_WTHH + ((size_t)(l * 4 + hcT) * 128) * 128;
    for (int k = 0; k < Kin; k++) Pih[k * 128 + colp] = Wih[gc * Kin + k];
    for (int k = 0; k < 128; k++) Phh[k * 128 + colp] = Whh[gc * 128 + k];
    ws[OFF_BIAS + (l * 4 + hcT) * 128 + colp] = bih[gc] + bhh[gc];
}

// grid = 192 blocks: layer = blockIdx/64 processes t = s - layer (wavefront).
// Per layer: 64 tiles = 16 row-tiles(16 rows) x 4 hcol-tiles(32 hcols).
// Thread register blocking: 2 rows x 4 gate-cols (one float4 of the permuted panel).
__global__ __launch_bounds__(256) void step_kernel(const float* __restrict__ x,
                                                   float* __restrict__ ws, int s)
{
    const float* Wt_ih = ws;
    const float* Wt_hh = ws + OFF_WTHH;
    const float* bias  = ws + OFF_BIAS;
    float* hbuf = ws + OFF_HBUF;
    float* cbuf = ws + OFF_CBUF;

    int layer = blockIdx.x >> 6;
    int t = s - layer;
    if (t < 0 || t >= Tt) return;
    int tile = blockIdx.x & 63;
    int r0  = (tile & 15) << 4;   // batch rows [r0, r0+16)
    int hcT = tile >> 4;          // hidden col tile (32 wide)
    int tid = threadIdx.x;
    int q   = tid & 31;           // column-quad index: cols q*4..q*4+3 (permuted)
    int rg  = tid >> 5;           // row-group: rows rg*2, rg*2+1
    int row0 = rg * 2, row1 = rg * 2 + 1;

    __shared__ float sAin[16][128];
    __shared__ float sArec[16][128];
    __shared__ float sG[16][136];

    int prev = (s - 1) & 1, cur = s & 1;
    const float* hprev_rec = hbuf + ((size_t)prev * 3 + layer) * Bsz * Hh;

    // ---- stage A tiles into LDS ----
    if (layer == 0) {
        if (tid < 128) {
            int r = tid >> 3, i = tid & 7;
            sAin[r][i] = x[((size_t)(r0 + r) * Tt + t) * 8 + i];
        }
    } else {
        const float* hprev_in = hbuf + ((size_t)prev * 3 + (layer - 1)) * Bsz * Hh;
        int e = tid * 8; int r = e >> 7, k = e & 127;
        const float* src = hprev_in + (size_t)(r0 + r) * Hh + k;
        *(float4*)&sAin[r][k]     = *(const float4*)(src);
        *(float4*)&sAin[r][k + 4] = *(const float4*)(src + 4);
    }
    if (t > 0) {
        int e = tid * 8; int r = e >> 7, k = e & 127;
        const float* src = hprev_rec + (size_t)(r0 + r) * Hh + k;
        *(float4*)&sArec[r][k]     = *(const float4*)(src);
        *(float4*)&sArec[r][k + 4] = *(const float4*)(src + 4);
    }
    __syncthreads();

    // ---- GEMM: 2 rows x 4 cols per thread ----
    float4 bb = *(const float4*)&bias[(layer * 4 + hcT) * 128 + q * 4];
    float acc0[4] = {bb.x, bb.y, bb.z, bb.w};
    float acc1[4] = {bb.x, bb.y, bb.z, bb.w};

    {   // input contribution
        const float* Wp = Wt_ih + ((size_t)(layer * 4 + hcT) * 128) * 128 + q * 4;
        int nk4 = (layer == 0) ? 2 : 32;
#pragma unroll 8
        for (int k4 = 0; k4 < nk4; ++k4) {
            int k = k4 * 4;
            float4 w0 = *(const float4*)&Wp[(k + 0) * 128];
            float4 w1 = *(const float4*)&Wp[(k + 1) * 128];
            float4 w2 = *(const float4*)&Wp[(k + 2) * 128];
            float4 w3 = *(const float4*)&Wp[(k + 3) * 128];
            float4 a0 = *(const float4*)&sAin[row0][k];
            float4 a1 = *(const float4*)&sAin[row1][k];
            acc0[0] += a0.x*w0.x + a0.y*w1.x + a0.z*w2.x + a0.w*w3.x;
            acc0[1] += a0.x*w0.y + a0.y*w1.y + a0.z*w2.y + a0.w*w3.y;
            acc0[2] += a0.x*w0.z + a0.y*w1.z + a0.z*w2.z + a0.w*w3.z;
            acc0[3] += a0.x*w0.w + a0.y*w1.w + a0.z*w2.w + a0.w*w3.w;
            acc1[0] += a1.x*w0.x + a1.y*w1.x + a1.z*w2.x + a1.w*w3.x;
            acc1[1] += a1.x*w0.y + a1.y*w1.y + a1.z*w2.y + a1.w*w3.y;
            acc1[2] += a1.x*w0.z + a1.y*w1.z + a1.z*w2.z + a1.w*w3.z;
            acc1[3] += a1.x*w0.w + a1.y*w1.w + a1.z*w2.w + a1.w*w3.w;
        }
    }
    if (t > 0) {  // recurrent contribution
        const float* Wp = Wt_hh + ((size_t)(layer * 4 + hcT) * 128) * 128 + q * 4;
#pragma unroll 8
        for (int k4 = 0; k4 < 32; ++k4) {
            int k = k4 * 4;
            float4 w0 = *(const float4*)&Wp[(k + 0) * 128];
            float4 w1 = *(const float4*)&Wp[(k + 1) * 128];
            float4 w2 = *(const float4*)&Wp[(k + 2) * 128];
            float4 w3 = *(const float4*)&Wp[(k + 3) * 128];
            float4 a0 = *(const float4*)&sArec[row0][k];
            float4 a1 = *(const float4*)&sArec[row1][k];
            acc0[0] += a0.x*w0.x + a0.y*w1.x + a0.z*w2.x + a0.w*w3.x;
            acc0[1] += a0.x*w0.y + a0.y*w1.y + a0.z*w2.y + a0.w*w3.y;
            acc0[2] += a0.x*w0.z + a0.y*w1.z + a0.z*w2.z + a0.w*w3.z;
            acc0[3] += a0.x*w0.w + a0.y*w1.w + a0.z*w2.w + a0.w*w3.w;
            acc1[0] += a1.x*w0.x + a1.y*w1.x + a1.z*w2.x + a1.w*w3.x;
            acc1[1] += a1.x*w0.y + a1.y*w1.y + a1.z*w2.y + a1.w*w3.y;
            acc1[2] += a1.x*w0.z + a1.y*w1.z + a1.z*w2.z + a1.w*w3.z;
            acc1[3] += a1.x*w0.w + a1.y*w1.w + a1.z*w2.w + a1.w*w3.w;
        }
    }
    *(float4*)&sG[row0][q * 4] = make_float4(acc0[0], acc0[1], acc0[2], acc0[3]);
    *(float4*)&sG[row1][q * 4] = make_float4(acc1[0], acc1[1], acc1[2], acc1[3]);
    __syncthreads();

    // ---- LSTM cell update: 512 cells / block, 2 per thread ----
    float* hcur = hbuf + ((size_t)cur * 3 + layer) * Bsz * Hh;
    float* cl   = cbuf + (size_t)layer * Bsz * Hh;
#pragma unroll
    for (int u = 0; u < 2; ++u) {
        int idx = tid + u * 256;
        int r = idx >> 5, wc = idx & 31;
        float gi = sG[r][wc],      gf = sG[r][32 + wc];
        float gg = sG[r][64 + wc], go = sG[r][96 + wc];
        size_t off = (size_t)(r0 + r) * Hh + hcT * 32 + wc;
        float cp = (t > 0) ? cl[off] : 0.f;
        float si = 1.f / (1.f + __expf(-gi));
        float sf = 1.f / (1.f + __expf(-gf));
        float so = 1.f / (1.f + __expf(-go));
        float cn = sf * cp + si * tanhf(gg);
        cl[off]   = cn;
        hcur[off] = so * tanhf(cn);
    }
}

__global__ void fc_kernel(const float* __restrict__ ws, const float* __restrict__ Wfc,
                          const float* __restrict__ bfc, float* __restrict__ out)
{
    // final h of layer2 written at s=513 -> hbuf[1][2]
    const float* h2 = ws + OFF_HBUF + (size_t)(1 * 3 + 2) * Bsz * Hh;
    int b = threadIdx.x;   // 256 threads
    float a0 = bfc[0], a1 = bfc[1], a2 = bfc[2];
    for (int k = 0; k < 128; k++) {
        float h = h2[b * 128 + k];
        a0 += h * Wfc[0 * 128 + k];
        a1 += h * Wfc[1 * 128 + k];
        a2 += h * Wfc[2 * 128 + k];
    }
    out[b * 3 + 0] = a0;
    out[b * 3 + 1] = a1;
    out[b * 3 + 2] = a2;
}

extern "C" void kernel_launch(void* const* d_in, const int* in_sizes, int n_in,
                              void* d_out, int out_size, void* d_ws, size_t ws_size,
                              hipStream_t stream)
{
    const float* x = (const float*)d_in[0];
    float* ws = (float*)d_ws;

    prep_kernel<<<6, 256, 0, stream>>>(
        (const float*)d_in[1],  (const float*)d_in[2],  (const float*)d_in[3],  (const float*)d_in[4],
        (const float*)d_in[5],  (const float*)d_in[6],  (const float*)d_in[7],  (const float*)d_in[8],
        (const float*)d_in[9],  (const float*)d_in[10], (const float*)d_in[11], (const float*)d_in[12],
        ws);

    for (int s = 0; s < Tt + 2; ++s)
        step_kernel<<<192, 256, 0, stream>>>(x, ws, s);

    fc_kernel<<<1, 256, 0, stream>>>(ws, (const float*)d_in[13], (const float*)d_in[14], (float*)d_out);
}

// Round 4
// 8833.337 us; speedup vs baseline: 1.1533x; 1.1533x over previous
//
#include <hip/hip_runtime.h>

#define Bsz 256
#define Tt  512
#define Hh  128

// ws layout (floats):
//   Wt_ih [3][4][128][128]  per-block panels: [layer][hcTile][k][colp], colp = gate*32+wc
//   Wt_hh [3][4][128][128]
//   bias  [3][4][128]
//   hbuf  [2][3][256][128]  double-buffered hidden states (parity = t&1)
//   cnt/ack counters (unsigned): cnt[3][16] @ OFF_CNT, ack[3][16] @ OFF_CNT+64
#define OFF_WTHH 196608
#define OFF_BIAS 393216
#define OFF_HBUF 394752
#define OFF_CNT  591360
// total ~591488 floats = 2.37 MB (< ws proven >= 2.76 MB in R2)

__global__ void prep_kernel(const float* Wih0, const float* Whh0, const float* bih0, const float* bhh0,
                            const float* Wih1, const float* Whh1, const float* bih1, const float* bhh1,
                            const float* Wih2, const float* Whh2, const float* bih2, const float* bhh2,
                            float* ws)
{
    int gid = blockIdx.x * blockDim.x + threadIdx.x;   // 0..1535
    if (gid < 128) ((unsigned*)(ws + OFF_CNT))[gid] = 0u;   // zero cnt+ack
    if (gid >= 3 * 512) return;
    int l = gid >> 9, gc = gid & 511;
    const float* Wih = (l == 0) ? Wih0 : (l == 1) ? Wih1 : Wih2;
    const float* Whh = (l == 0) ? Whh0 : (l == 1) ? Whh1 : Whh2;
    const float* bih = (l == 0) ? bih0 : (l == 1) ? bih1 : bih2;
    const float* bhh = (l == 0) ? bhh0 : (l == 1) ? bhh1 : bhh2;
    int Kin = (l == 0) ? 8 : 128;
    int gate = gc >> 7, hcT = (gc >> 5) & 3, wc = gc & 31;
    int colp = gate * 32 + wc;
    float* Pih = ws + ((size_t)(l * 4 + hcT) * 128) * 128;
    float* Phh = ws + OFF_WTHH + ((size_t)(l * 4 + hcT) * 128) * 128;
    for (int k = 0; k < Kin; k++) Pih[k * 128 + colp] = Wih[gc * Kin + k];
    for (int k = 0; k < 128; k++) Phh[k * 128 + colp] = Whh[gc * 128 + k];
    ws[OFF_BIAS + (l * 4 + hcT) * 128 + colp] = bih[gc] + bhh[gc];
}

__device__ __forceinline__ void spin_ge(unsigned* p, unsigned tgt) {
    while (__hip_atomic_load(p, __ATOMIC_RELAXED, __HIP_MEMORY_SCOPE_AGENT) < tgt)
        __builtin_amdgcn_s_sleep(1);
}

// Persistent wavefront LSTM. 192 blocks = 3 layers x 16 rowtiles x 4 hcol-tiles.
// 156 KB LDS/block forces 1 block/CU -> all 192 co-resident on 256 CUs.
__global__ __launch_bounds__(256, 1) void lstm_persistent(const float* __restrict__ x,
                                                          float* __restrict__ ws)
{
    __shared__ float sWih[128 * 128];
    __shared__ float sWhh[128 * 128];
    __shared__ float sA[2][16][132];   // [0]=input tile, [1]=recurrent tile (pad 132)
    __shared__ float sG[16][132];

    const int bid   = blockIdx.x;
    const int layer = bid >> 6;
    const int tile  = bid & 63;
    const int rT    = tile & 15;
    const int r0    = rT << 4;
    const int hcT   = tile >> 4;
    const int tid   = threadIdx.x;

    // ---- load weight panels into LDS once ----
    {
        const float* gWih = ws + ((size_t)(layer * 4 + hcT) * 128) * 128;
        const float* gWhh = ws + OFF_WTHH + ((size_t)(layer * 4 + hcT) * 128) * 128;
        for (int i = tid * 4; i < 16384; i += 1024) {
            *(float4*)&sWih[i] = *(const float4*)&gWih[i];
            *(float4*)&sWhh[i] = *(const float4*)&gWhh[i];
        }
    }

    // lane mapping: per wave 16 col-quads x 4 row-groups (4-way weight broadcast)
    const int wv   = tid >> 6, ln = tid & 63;
    const int qg   = ((wv & 1) << 4) + (ln & 15);   // col-quad 0..31
    const int rg   = ((wv >> 1) << 2) + (ln >> 4);  // row-group 0..7
    const int row0 = rg << 1, row1 = row0 + 1;
    const int cq4  = qg << 2;

    const float4 b4 = *(const float4*)&ws[OFF_BIAS + (layer * 4 + hcT) * 128 + cq4];

    unsigned* cnt     = (unsigned*)(ws + OFF_CNT);
    unsigned* ack     = cnt + 64;
    unsigned* cnt_own = &cnt[layer * 16 + rT];
    unsigned* cnt_in  = &cnt[(layer - 1) * 16 + rT];
    unsigned* ack_own = &ack[layer * 16 + rT];
    unsigned* ack_up  = &ack[(layer - 1) * 16 + rT];

    float* hb = ws + OFF_HBUF;

    // cell state in registers (fixed thread->cell map across steps)
    float c0 = 0.f, c1 = 0.f;
    const int cr0 = tid >> 5, cw = tid & 31;
    const int cr1 = (tid + 256) >> 5;

    __syncthreads();

    for (int t = 0; t < Tt; ++t) {
        // ---- dependency waits ----
        if (tid == 0) {
            if (t > 0)               spin_ge(cnt_own, 4u * (unsigned)t);          // siblings wrote h_{t-1}
            if (layer > 0)           spin_ge(cnt_in,  4u * (unsigned)(t + 1));    // layer-1 wrote h_t
            if (layer < 2 && t >= 2) spin_ge(ack_own, 4u * (unsigned)(t - 1));    // consumers staged h_{t-2}
            __threadfence();   // acquire: invalidate L1/L2 so staging reads fresh h
        }
        __syncthreads();

        // ---- stage A tiles into LDS ----
        if (layer == 0) {
            if (tid < 128) {
                int r = tid >> 3, i = tid & 7;
                sA[0][r][i] = x[((size_t)(r0 + r) * Tt + t) * 8 + i];
            }
        } else {
            const float* hin = hb + ((size_t)(t & 1) * 3 + (layer - 1)) * (Bsz * Hh);
            int e = tid * 8, r = e >> 7, k = e & 127;
            const float* src = hin + (size_t)(r0 + r) * Hh + k;
            *(float4*)&sA[0][r][k]     = *(const float4*)src;
            *(float4*)&sA[0][r][k + 4] = *(const float4*)(src + 4);
        }
        if (t > 0) {
            const float* hrec = hb + ((size_t)((t - 1) & 1) * 3 + layer) * (Bsz * Hh);
            int e = tid * 8, r = e >> 7, k = e & 127;
            const float* src = hrec + (size_t)(r0 + r) * Hh + k;
            *(float4*)&sA[1][r][k]     = *(const float4*)src;
            *(float4*)&sA[1][r][k + 4] = *(const float4*)(src + 4);
        }
        __syncthreads();
        if (tid == 0 && layer > 0)
            __hip_atomic_fetch_add(ack_up, 1u, __ATOMIC_RELEASE, __HIP_MEMORY_SCOPE_AGENT);

        // ---- GEMM: 2 rows x 4 cols per thread, weights from LDS ----
        float acc[8] = {b4.x, b4.y, b4.z, b4.w, b4.x, b4.y, b4.z, b4.w};

#define GEMM_STEP(SW, AB, K)                                              \
        {                                                                 \
            float4 w0 = *(const float4*)&SW[((K) + 0) * 128 + cq4];       \
            float4 w1 = *(const float4*)&SW[((K) + 1) * 128 + cq4];       \
            float4 w2 = *(const float4*)&SW[((K) + 2) * 128 + cq4];       \
            float4 w3 = *(const float4*)&SW[((K) + 3) * 128 + cq4];       \
            float4 a0 = *(const float4*)&sA[AB][row0][(K)];               \
            float4 a1 = *(const float4*)&sA[AB][row1][(K)];               \
            acc[0] += a0.x*w0.x + a0.y*w1.x + a0.z*w2.x + a0.w*w3.x;      \
            acc[1] += a0.x*w0.y + a0.y*w1.y + a0.z*w2.y + a0.w*w3.y;      \
            acc[2] += a0.x*w0.z + a0.y*w1.z + a0.z*w2.z + a0.w*w3.z;      \
            acc[3] += a0.x*w0.w + a0.y*w1.w + a0.z*w2.w + a0.w*w3.w;      \
            acc[4] += a1.x*w0.x + a1.y*w1.x + a1.z*w2.x + a1.w*w3.x;      \
            acc[5] += a1.x*w0.y + a1.y*w1.y + a1.z*w2.y + a1.w*w3.y;      \
            acc[6] += a1.x*w0.z + a1.y*w1.z + a1.z*w2.z + a1.w*w3.z;      \
            acc[7] += a1.x*w0.w + a1.y*w1.w + a1.z*w2.w + a1.w*w3.w;      \
        }

        {
            const int nk4 = (layer == 0) ? 2 : 32;
#pragma unroll 4
            for (int k4 = 0; k4 < nk4; ++k4) GEMM_STEP(sWih, 0, k4 * 4)
        }
        if (t > 0) {
#pragma unroll 4
            for (int k4 = 0; k4 < 32; ++k4) GEMM_STEP(sWhh, 1, k4 * 4)
        }
#undef GEMM_STEP

        *(float4*)&sG[row0][cq4] = make_float4(acc[0], acc[1], acc[2], acc[3]);
        *(float4*)&sG[row1][cq4] = make_float4(acc[4], acc[5], acc[6], acc[7]);
        __syncthreads();

        // ---- LSTM cell update (c in regs) + h store ----
        float* hcur = hb + ((size_t)(t & 1) * 3 + layer) * (Bsz * Hh);
        {
            float gi = sG[cr0][cw], gf = sG[cr0][32 + cw];
            float gg = sG[cr0][64 + cw], go = sG[cr0][96 + cw];
            float si = 1.f / (1.f + __expf(-gi));
            float sf = 1.f / (1.f + __expf(-gf));
            float so = 1.f / (1.f + __expf(-go));
            float cn = sf * c0 + si * tanhf(gg);
            c0 = cn;
            hcur[(size_t)(r0 + cr0) * Hh + (hcT << 5) + cw] = so * tanhf(cn);
        }
        {
            float gi = sG[cr1][cw], gf = sG[cr1][32 + cw];
            float gg = sG[cr1][64 + cw], go = sG[cr1][96 + cw];
            float si = 1.f / (1.f + __expf(-gi));
            float sf = 1.f / (1.f + __expf(-gf));
            float so = 1.f / (1.f + __expf(-go));
            float cn = sf * c1 + si * tanhf(gg);
            c1 = cn;
            hcur[(size_t)(r0 + cr1) * Hh + (hcT << 5) + cw] = so * tanhf(cn);
        }
        __syncthreads();   // drain all waves' h stores (barrier implies vmcnt(0))
        if (tid == 0) {
            __threadfence();   // release: push h to coherence point (wbl2)
            __hip_atomic_fetch_add(cnt_own, 1u, __ATOMIC_RELEASE, __HIP_MEMORY_SCOPE_AGENT);
        }
    }
}

__global__ void fc_kernel(const float* __restrict__ ws, const float* __restrict__ Wfc,
                          const float* __restrict__ bfc, float* __restrict__ out)
{
    // final h of layer2 at t=511 -> parity 1 -> hbuf[1][2]
    const float* h2 = ws + OFF_HBUF + (size_t)(1 * 3 + 2) * Bsz * Hh;
    int b = threadIdx.x;   // 256 threads
    float a0 = bfc[0], a1 = bfc[1], a2 = bfc[2];
    for (int k = 0; k < 128; k++) {
        float h = h2[b * 128 + k];
        a0 += h * Wfc[0 * 128 + k];
        a1 += h * Wfc[1 * 128 + k];
        a2 += h * Wfc[2 * 128 + k];
    }
    out[b * 3 + 0] = a0;
    out[b * 3 + 1] = a1;
    out[b * 3 + 2] = a2;
}

extern "C" void kernel_launch(void* const* d_in, const int* in_sizes, int n_in,
                              void* d_out, int out_size, void* d_ws, size_t ws_size,
                              hipStream_t stream)
{
    const float* x = (const float*)d_in[0];
    float* ws = (float*)d_ws;

    prep_kernel<<<6, 256, 0, stream>>>(
        (const float*)d_in[1],  (const float*)d_in[2],  (const float*)d_in[3],  (const float*)d_in[4],
        (const float*)d_in[5],  (const float*)d_in[6],  (const float*)d_in[7],  (const float*)d_in[8],
        (const float*)d_in[9],  (const float*)d_in[10], (const float*)d_in[11], (const float*)d_in[12],
        ws);

    lstm_persistent<<<192, 256, 0, stream>>>(x, ws);

    fc_kernel<<<1, 256, 0, stream>>>(ws, (const float*)d_in[13], (const float*)d_in[14], (float*)d_out);
}